// Round 2
// baseline (426.377 us; speedup 1.0000x reference)
//
#include <hip/hip_runtime.h>

// FWHT of 2^26 fp32 elements in TWO passes over memory (was three):
//   K1: bits 0..13  (contiguous lines of 16384 floats, LDS-resident)
//   K2: bits 14..25 (stride 2^14; 6 bits in regs + LDS exchange + 6 bits in regs)
// All butterfly stages commute, so this equals the reference's order.

// ---------------- K1: low 14 bits ----------------
__global__ __launch_bounds__(512) void fwht_low14(const float* __restrict__ in,
                                                  float* __restrict__ out) {
    __shared__ float lds[16384];                     // 64 KB
    const int t = threadIdx.x;
    const size_t base = (size_t)blockIdx.x * 16384;
    const float4* in4 = reinterpret_cast<const float4*>(in + base);
    float4* out4 = reinterpret_cast<float4*>(out + base);
    float4* lds4 = reinterpret_cast<float4*>(lds);

    // Load + butterfly bits 0,1 inside each float4 (register-only)
    #pragma unroll
    for (int k = 0; k < 8; ++k) {
        float4 v = in4[t + 512 * k];
        float a0 = v.x + v.y, a1 = v.x - v.y;
        float a2 = v.z + v.w, a3 = v.z - v.w;
        float4 w;
        w.x = a0 + a2; w.y = a1 + a3;
        w.z = a0 - a2; w.w = a1 - a3;
        lds4[t + 512 * k] = w;
    }
    __syncthreads();

    // Bits 2..13: quad-aligned butterflies in LDS (h4 = distance in float4 units)
    #pragma unroll
    for (int h4 = 1; h4 <= 2048; h4 <<= 1) {
        #pragma unroll
        for (int k = 0; k < 4; ++k) {
            int q = t + 512 * k;                     // quad-pair id, 0..2047
            int j = ((q & ~(h4 - 1)) << 1) | (q & (h4 - 1));
            float4 a = lds4[j];
            float4 b = lds4[j + h4];
            float4 s, d;
            s.x = a.x + b.x; s.y = a.y + b.y; s.z = a.z + b.z; s.w = a.w + b.w;
            d.x = a.x - b.x; d.y = a.y - b.y; d.z = a.z - b.z; d.w = a.w - b.w;
            lds4[j] = s;
            lds4[j + h4] = d;
        }
        __syncthreads();
    }

    #pragma unroll
    for (int k = 0; k < 8; ++k)
        out4[t + 512 * k] = lds4[t + 512 * k];
}

// ---------------- K2: high 12 bits (14..25), row stride 2^14 ----------------
// Block owns 4 columns x 4096 rows. Phase 1: rows g+64j (j = row bits 6..11,
// global bits 20..25) butterflied in registers. LDS exchange (XOR-swizzled).
// Phase 2: rows 64g+s (s = row bits 0..5, global bits 14..19) in registers.
__device__ __forceinline__ int swz(int a) {
    return a ^ (((a >> 8) & 7) << 2);   // XOR addr bits 8..10 into 2..4 (involution)
}

__global__ __launch_bounds__(256) void fwht_high12(float* __restrict__ data) {
    __shared__ float lds[16384];                     // 64 KB
    const int t = threadIdx.x;
    const int c = t & 3;                             // column within tile
    const int g = t >> 2;                            // 0..63
    const int b = blockIdx.x;
    // XCD-aware swizzle: the 8 blocks sharing each 128B line run on one XCD.
    const int colTile = (b & 7) * 512 + (b >> 3);    // bijective, 4096 tiles
    const size_t col = (size_t)colTile * 4 + c;      // global bits 0..13

    float v[64];

    // Phase 1 load: rows r = g + 64*j
    #pragma unroll
    for (int j = 0; j < 64; ++j)
        v[j] = data[((size_t)(g + 64 * j) << 14) + col];

    // Butterfly row bits 6..11 (global bits 20..25) over j
    #pragma unroll
    for (int h = 1; h < 64; h <<= 1) {
        #pragma unroll
        for (int base0 = 0; base0 < 64; base0 += 2 * h) {
            #pragma unroll
            for (int k = 0; k < h; ++k) {
                float a = v[base0 + k];
                float bb = v[base0 + k + h];
                v[base0 + k] = a + bb;
                v[base0 + k + h] = a - bb;
            }
        }
    }

    // Exchange through LDS: linear layout lds[row*4 + c], XOR-swizzled
    #pragma unroll
    for (int j = 0; j < 64; ++j)
        lds[swz((g + 64 * j) * 4 + c)] = v[j];
    __syncthreads();
    #pragma unroll
    for (int s = 0; s < 64; ++s)
        v[s] = lds[swz((64 * g + s) * 4 + c)];

    // Butterfly row bits 0..5 (global bits 14..19) over s
    #pragma unroll
    for (int h = 1; h < 64; h <<= 1) {
        #pragma unroll
        for (int base0 = 0; base0 < 64; base0 += 2 * h) {
            #pragma unroll
            for (int k = 0; k < h; ++k) {
                float a = v[base0 + k];
                float bb = v[base0 + k + h];
                v[base0 + k] = a + bb;
                v[base0 + k + h] = a - bb;
            }
        }
    }

    // Store rows 64g + s
    #pragma unroll
    for (int s = 0; s < 64; ++s)
        data[((size_t)(64 * g + s) << 14) + col] = v[s];
}

extern "C" void kernel_launch(void* const* d_in, const int* in_sizes, int n_in,
                              void* d_out, int out_size, void* d_ws, size_t ws_size,
                              hipStream_t stream) {
    const float* x = (const float*)d_in[0];
    float* out = (float*)d_out;
    fwht_low14<<<4096, 512, 0, stream>>>(x, out);    // bits 0..13, in -> out
    fwht_high12<<<4096, 256, 0, stream>>>(out);      // bits 14..25, in place
}

// Round 4
// 247.550 us; speedup vs baseline: 1.7224x; 1.7224x over previous
//
#include <hip/hip_runtime.h>

// FWHT of 2^26 fp32 in TWO fully line-coalesced passes:
//   Pass 1 (fwht_low15):  bits 0..14  — contiguous 32K-float blocks.
//       regs: bits 0,1 (intra-float4) + bits 12,13,14 (across 8 float4/thread)
//       LDS : bits 2..11 (radix-4 stages on float4 quads, two 64KB halves,
//             XOR-swizzled addresses for conflict-free strides)
//   Pass 2 (fwht_high11): bits 15..25 — 32-col x 2048-row blocks (full 128B lines).
//       regs: bits 20..25 (6-bit ladder) ; LDS exchange (4 x 64KB chunks) ;
//       regs: bits 15..19 (5-bit ladder)
// All butterfly stages commute; sum goes to the lower index (matches reference).

typedef float nvf4 __attribute__((ext_vector_type(4)));

__device__ __forceinline__ float4 add4(float4 a, float4 b) {
    return make_float4(a.x + b.x, a.y + b.y, a.z + b.z, a.w + b.w);
}
__device__ __forceinline__ float4 sub4(float4 a, float4 b) {
    return make_float4(a.x - b.x, a.y - b.y, a.z - b.z, a.w - b.w);
}
// LDS float4-index swizzle: spreads q%8 (bank group) with q bits 3..5.
__device__ __forceinline__ int SWZ(int q) { return q ^ ((q >> 3) & 7); }

// ---------------- Pass 1: bits 0..14 ----------------
__global__ __launch_bounds__(1024) void fwht_low15(const float* __restrict__ in,
                                                   float* __restrict__ out) {
    __shared__ float4 lds4[4096];                    // 64 KB
    const int t = threadIdx.x;
    const size_t base4 = (size_t)blockIdx.x * 8192;  // float4 units
    const nvf4* in4 = reinterpret_cast<const nvf4*>(in) + base4;
    float4* out4 = reinterpret_cast<float4*>(out) + base4;

    float4 v[8];
    // Load (nontemporal: x is read exactly once) + intra-quad butterflies (bits 0,1)
    #pragma unroll
    for (int k = 0; k < 8; ++k) {
        nvf4 xv = __builtin_nontemporal_load(in4 + t + 1024 * k);
        float a0 = xv[0] + xv[1], a1 = xv[0] - xv[1];
        float a2 = xv[2] + xv[3], a3 = xv[2] - xv[3];
        v[k] = make_float4(a0 + a2, a1 + a3, a0 - a2, a1 - a3);
    }
    // Cross-k ladder: quad bits 10..12 = float bits 12..14
    #pragma unroll
    for (int h = 1; h < 8; h <<= 1) {
        #pragma unroll
        for (int i = 0; i < 8; i += 2 * h) {
            #pragma unroll
            for (int k = 0; k < h; ++k) {
                float4 a = v[i + k], b = v[i + k + h];
                v[i + k] = add4(a, b);
                v[i + k + h] = sub4(a, b);
            }
        }
    }

    // LDS: quad bits 0..9 (= float bits 2..11), radix-4, two halves of 4 k-groups
    const int kkg = t >> 8;          // which k-slot this thread processes (0..3)
    const int p = t & 255;           // radix-4 node within the 1024-quad group
    #pragma unroll
    for (int half = 0; half < 2; ++half) {
        #pragma unroll
        for (int k2 = 0; k2 < 4; ++k2)
            lds4[SWZ(k2 * 1024 + t)] = v[half * 4 + k2];
        __syncthreads();

        #pragma unroll
        for (int h4 = 1; h4 <= 256; h4 <<= 2) {      // 1,4,16,64,256
            const int j = ((p & ~(h4 - 1)) << 2) | (p & (h4 - 1));
            const int a0i = kkg * 1024 + j;
            // Each thread exclusively owns these 4 quads this stage: no
            // read->write barrier needed, only the end-of-stage barrier.
            float4 x0 = lds4[SWZ(a0i)];
            float4 x1 = lds4[SWZ(a0i + h4)];
            float4 x2 = lds4[SWZ(a0i + 2 * h4)];
            float4 x3 = lds4[SWZ(a0i + 3 * h4)];
            float4 b0 = add4(x0, x1), b1 = sub4(x0, x1);
            float4 b2 = add4(x2, x3), b3 = sub4(x2, x3);
            lds4[SWZ(a0i)] = add4(b0, b2);
            lds4[SWZ(a0i + h4)] = add4(b1, b3);
            lds4[SWZ(a0i + 2 * h4)] = sub4(b0, b2);
            lds4[SWZ(a0i + 3 * h4)] = sub4(b1, b3);
            __syncthreads();
        }

        #pragma unroll
        for (int k2 = 0; k2 < 4; ++k2)
            v[half * 4 + k2] = lds4[SWZ(k2 * 1024 + t)];
        if (half == 0) __syncthreads();              // before next half overwrites
    }

    #pragma unroll
    for (int k = 0; k < 8; ++k)
        out4[t + 1024 * k] = v[k];
}

// ---------------- Pass 2: bits 15..25 ----------------
// Block: 32 columns x 2048 rows (row stride 2^15 floats). 1024 threads.
// Thread (c = t&31, g = t>>5) holds rows g + 32*j, j=0..63 -> v[64].
// Phase A: 6-bit ladder over j (global bits 20..25).
// Exchange via LDS in 4 chunks of 16 j-values (64 KB each); readers of chunk m
// are threads t in [256m, 256m+256), which butterfly global bits 15..19 and
// store immediately (full 128B lines, nontemporal).
__global__ __launch_bounds__(1024) void fwht_high11(float* __restrict__ data) {
    __shared__ float lds[16384];                     // 64 KB
    const int t = threadIdx.x;
    const int c = t & 31;
    const int g = t >> 5;                            // 0..31
    const size_t col = (size_t)blockIdx.x * 32 + c;

    float v[64];
    #pragma unroll
    for (int j = 0; j < 64; ++j)
        v[j] = data[((size_t)(g + 32 * j) << 15) + col];

    // Phase A: bits 20..25 over j
    #pragma unroll
    for (int h = 1; h < 64; h <<= 1) {
        #pragma unroll
        for (int i = 0; i < 64; i += 2 * h) {
            #pragma unroll
            for (int k = 0; k < h; ++k) {
                float a = v[i + k], b = v[i + k + h];
                v[i + k] = a + b;
                v[i + k + h] = a - b;
            }
        }
    }

    // Exchange + Phase B, chunked
    #pragma unroll
    for (int m = 0; m < 4; ++m) {
        __syncthreads();                             // prev chunk readers done
        #pragma unroll
        for (int jj = 0; jj < 16; ++jj)
            lds[jj * 1024 + g * 32 + c] = v[16 * m + jj];
        __syncthreads();

        if ((t >> 8) == m) {                         // 256 reader threads
            const int local = t & 255;
            const int cr = local & 31;
            const int gbl = local >> 5;              // 0..7
            const int gb = 8 * m + gbl;              // row bits 6..10
            const size_t colr = (size_t)blockIdx.x * 32 + cr;
            #pragma unroll
            for (int hf = 0; hf < 2; ++hf) {
                float w[32];
                #pragma unroll
                for (int s = 0; s < 32; ++s)
                    w[s] = lds[(2 * gbl + hf) * 1024 + s * 32 + cr];
                // Phase B: bits 15..19 over s
                #pragma unroll
                for (int h = 1; h < 32; h <<= 1) {
                    #pragma unroll
                    for (int i = 0; i < 32; i += 2 * h) {
                        #pragma unroll
                        for (int k = 0; k < h; ++k) {
                            float a = w[i + k], b = w[i + k + h];
                            w[i + k] = a + b;
                            w[i + k + h] = a - b;
                        }
                    }
                }
                #pragma unroll
                for (int s = 0; s < 32; ++s)
                    __builtin_nontemporal_store(
                        w[s], &data[((size_t)(64 * gb + 32 * hf + s) << 15) + colr]);
            }
        }
    }
}

extern "C" void kernel_launch(void* const* d_in, const int* in_sizes, int n_in,
                              void* d_out, int out_size, void* d_ws, size_t ws_size,
                              hipStream_t stream) {
    const float* x = (const float*)d_in[0];
    float* out = (float*)d_out;
    fwht_low15<<<2048, 1024, 0, stream>>>(x, out);   // bits 0..14, in -> out
    fwht_high11<<<1024, 1024, 0, stream>>>(out);     // bits 15..25, in place
}

// Round 5
// 203.636 us; speedup vs baseline: 2.0938x; 1.2156x over previous
//
#include <hip/hip_runtime.h>

// FWHT of 2^26 fp32 in TWO fully line-coalesced passes:
//   Pass 1 (fwht_low15):  bits 0..14 — contiguous 32K-float blocks, 128KB LDS.
//       regs: bits 0,1 (intra-float4) + bits 12,13,14 (across 8 float4/thread)
//       LDS : bits 2..11 — 5 radix-4 stages, XOR-swizzled (conflict-free),
//             each thread owns 2 radix-4 nodes/stage. 6 barriers total.
//   Pass 2 (fwht_high11): bits 15..25 — 32-col x 2048-row blocks (full 128B lines).
//       regs: bits 20..25 (6-bit ladder over j)
//       LDS : 2 chunks x 128KB transpose; ALL 1024 threads read back, ladder
//             bits 15..19 over s, store. 3 barriers total.
// All butterfly stages commute; sum goes to the lower index (matches reference).

typedef float nvf4 __attribute__((ext_vector_type(4)));

__device__ __forceinline__ float4 add4(float4 a, float4 b) {
    return make_float4(a.x + b.x, a.y + b.y, a.z + b.z, a.w + b.w);
}
__device__ __forceinline__ float4 sub4(float4 a, float4 b) {
    return make_float4(a.x - b.x, a.y - b.y, a.z - b.z, a.w - b.w);
}
// LDS float4-index swizzle: spreads bank-group (q%8) with q bits 3..5.
// Verified conflict-free for strides {1,4,16,64,256} and linear access.
__device__ __forceinline__ int SWZ(int q) { return q ^ ((q >> 3) & 7); }

// ---------------- Pass 1: bits 0..14 ----------------
__global__ __launch_bounds__(1024) void fwht_low15(const float* __restrict__ in,
                                                   float* __restrict__ out) {
    __shared__ float4 lds4[8192];                    // 128 KB
    const int t = threadIdx.x;
    const size_t base4 = (size_t)blockIdx.x * 8192;  // float4 units
    const nvf4* in4 = reinterpret_cast<const nvf4*>(in) + base4;
    float4* out4 = reinterpret_cast<float4*>(out) + base4;

    float4 v[8];
    // Load (nontemporal: input read exactly once) + intra-quad butterflies (bits 0,1)
    #pragma unroll
    for (int k = 0; k < 8; ++k) {
        nvf4 xv = __builtin_nontemporal_load(in4 + t + 1024 * k);
        float a0 = xv[0] + xv[1], a1 = xv[0] - xv[1];
        float a2 = xv[2] + xv[3], a3 = xv[2] - xv[3];
        v[k] = make_float4(a0 + a2, a1 + a3, a0 - a2, a1 - a3);
    }
    // Cross-k ladder: quad bits 10..12 = float bits 12..14
    #pragma unroll
    for (int h = 1; h < 8; h <<= 1) {
        #pragma unroll
        for (int i = 0; i < 8; i += 2 * h) {
            #pragma unroll
            for (int k = 0; k < h; ++k) {
                float4 a = v[i + k], b = v[i + k + h];
                v[i + k] = add4(a, b);
                v[i + k + h] = sub4(a, b);
            }
        }
    }

    // Store all 8 quads, then 5 radix-4 stages over quad bits 0..9 (float bits 2..11)
    #pragma unroll
    for (int k = 0; k < 8; ++k)
        lds4[SWZ(k * 1024 + t)] = v[k];
    __syncthreads();

    const int kkg = t >> 8;          // base k-group (0..3); thread also does kkg+4
    const int p = t & 255;           // radix-4 node within each 1024-quad group
    #pragma unroll
    for (int h4 = 1; h4 <= 256; h4 <<= 2) {          // 1,4,16,64,256
        const int j = ((p & ~(h4 - 1)) << 2) | (p & (h4 - 1));
        #pragma unroll
        for (int e = 0; e < 2; ++e) {                // two exclusive nodes/thread
            const int a0i = (kkg + 4 * e) * 1024 + j;
            float4 x0 = lds4[SWZ(a0i)];
            float4 x1 = lds4[SWZ(a0i + h4)];
            float4 x2 = lds4[SWZ(a0i + 2 * h4)];
            float4 x3 = lds4[SWZ(a0i + 3 * h4)];
            float4 b0 = add4(x0, x1), b1 = sub4(x0, x1);
            float4 b2 = add4(x2, x3), b3 = sub4(x2, x3);
            lds4[SWZ(a0i)] = add4(b0, b2);
            lds4[SWZ(a0i + h4)] = add4(b1, b3);
            lds4[SWZ(a0i + 2 * h4)] = sub4(b0, b2);
            lds4[SWZ(a0i + 3 * h4)] = sub4(b1, b3);
        }
        __syncthreads();
    }

    #pragma unroll
    for (int k = 0; k < 8; ++k)
        out4[t + 1024 * k] = lds4[SWZ(k * 1024 + t)];   // regular store: keep in L3
}

// ---------------- Pass 2: bits 15..25 ----------------
// Block: 32 columns x 2048 rows (row stride 2^15 floats). 1024 threads.
// Thread (c=t&31, g=t>>5) holds rows g+32j, j=0..63 in v[64].
// Phase A: 6-bit ladder over j (global bits 20..25).
// Two 128KB LDS chunks (32 j-values each); ALL threads read back one
// (j_local, c) column of 32 s-values, ladder bits 15..19, store full lines.
__global__ __launch_bounds__(1024) void fwht_high11(float* __restrict__ data) {
    __shared__ float lds[32768];                     // 128 KB
    const int t = threadIdx.x;
    const int c = t & 31;
    const int g = t >> 5;                            // 0..31 (reused as j_local)
    const size_t col = (size_t)blockIdx.x * 32 + c;

    float v[64];
    #pragma unroll
    for (int j = 0; j < 64; ++j)
        v[j] = data[((size_t)(g + 32 * j) << 15) + col];

    // Phase A: bits 20..25 over j
    #pragma unroll
    for (int h = 1; h < 64; h <<= 1) {
        #pragma unroll
        for (int i = 0; i < 64; i += 2 * h) {
            #pragma unroll
            for (int k = 0; k < h; ++k) {
                float a = v[i + k], b = v[i + k + h];
                v[i + k] = a + b;
                v[i + k + h] = a - b;
            }
        }
    }

    // Two chunks: transpose through LDS, ladder bits 15..19, store.
    #pragma unroll
    for (int m = 0; m < 2; ++m) {
        if (m) __syncthreads();                      // chunk-0 readers done
        #pragma unroll
        for (int jj = 0; jj < 32; ++jj)
            lds[jj * 1024 + g * 32 + c] = v[32 * m + jj];   // bank = c, free
        __syncthreads();

        float w[32];
        #pragma unroll
        for (int s = 0; s < 32; ++s)
            w[s] = lds[g * 1024 + s * 32 + c];       // j_local = g; bank = c, free
        // Phase B: bits 15..19 over s
        #pragma unroll
        for (int h = 1; h < 32; h <<= 1) {
            #pragma unroll
            for (int i = 0; i < 32; i += 2 * h) {
                #pragma unroll
                for (int k = 0; k < h; ++k) {
                    float a = w[i + k], b = w[i + k + h];
                    w[i + k] = a + b;
                    w[i + k + h] = a - b;
                }
            }
        }
        const int rowbase = 32 * (32 * m + g);
        #pragma unroll
        for (int s = 0; s < 32; ++s)
            __builtin_nontemporal_store(w[s], &data[((size_t)(rowbase + s) << 15) + col]);
    }
}

extern "C" void kernel_launch(void* const* d_in, const int* in_sizes, int n_in,
                              void* d_out, int out_size, void* d_ws, size_t ws_size,
                              hipStream_t stream) {
    const float* x = (const float*)d_in[0];
    float* out = (float*)d_out;
    fwht_low15<<<2048, 1024, 0, stream>>>(x, out);   // bits 0..14, in -> out
    fwht_high11<<<1024, 1024, 0, stream>>>(out);     // bits 15..25, in place
}

// Round 6
// 189.958 us; speedup vs baseline: 2.2446x; 1.0720x over previous
//
#include <hip/hip_runtime.h>

// FWHT of 2^26 fp32 in TWO fully line-coalesced passes:
//   Pass 1 (fwht_low15): bits 0..14 — 512-thread blocks over 2^15 floats,
//       64 KB LDS (2 blocks/CU).
//       regs: bits 0,1 (intra-float4) + bits 11..14 (16-quad k-ladder)
//       LDS : 3 exchanges (A/B/C), each a b128 quad-transpose giving 3 bits
//             (float bits 2..4, 5..7, 8..10), XOR-swizzled conflict-free.
//   Pass 2 (fwht_high11): bits 15..25 — 32-col x 2048-row blocks (full 128B lines).
//       regs: bits 20..25 ; LDS: 2 x 128KB transpose chunks ; regs: bits 15..19.
// All butterfly stages commute; sum goes to the lower index (matches reference).

typedef float nvf4 __attribute__((ext_vector_type(4)));

__device__ __forceinline__ float4 add4(float4 a, float4 b) {
    return make_float4(a.x + b.x, a.y + b.y, a.z + b.z, a.w + b.w);
}
__device__ __forceinline__ float4 sub4(float4 a, float4 b) {
    return make_float4(a.x - b.x, a.y - b.y, a.z - b.z, a.w - b.w);
}
// LDS float4-index swizzle: bank-group = a[2:0] ^ a[5:3]; conflict-free for all
// access patterns below (consecutive 8 lanes always hit 8 distinct groups).
__device__ __forceinline__ int SWZ(int q) { return q ^ ((q >> 3) & 7); }

// 3-stage FWHT ladder over u[0..7] (float4 SIMD)
__device__ __forceinline__ void lad3(float4* u) {
    #pragma unroll
    for (int h = 1; h < 8; h <<= 1) {
        #pragma unroll
        for (int i = 0; i < 8; i += 2 * h) {
            #pragma unroll
            for (int k = 0; k < h; ++k) {
                float4 a = u[i + k], b = u[i + k + h];
                u[i + k] = add4(a, b);
                u[i + k + h] = sub4(a, b);
            }
        }
    }
}

// ---------------- Pass 1: bits 0..14 ----------------
__global__ __launch_bounds__(512) void fwht_low15(const float* __restrict__ in,
                                                  float* __restrict__ out) {
    __shared__ float4 lds4[4096];                    // 64 KB (one half-block)
    const int t = threadIdx.x;                       // 0..511
    const size_t base4 = (size_t)blockIdx.x * 8192;  // float4 units
    const nvf4* in4 = reinterpret_cast<const nvf4*>(in) + base4;
    float4* out4 = reinterpret_cast<float4*>(out) + base4;

    float4 v[16];
    // Load 16 quads (nontemporal) + intra-quad butterflies (bits 0,1)
    #pragma unroll
    for (int k = 0; k < 16; ++k) {
        nvf4 xv = __builtin_nontemporal_load(in4 + t + 512 * k);
        float a0 = xv[0] + xv[1], a1 = xv[0] - xv[1];
        float a2 = xv[2] + xv[3], a3 = xv[2] - xv[3];
        v[k] = make_float4(a0 + a2, a1 + a3, a0 - a2, a1 - a3);
    }
    // k-ladder: quad bits 9..12 = float bits 11..14
    #pragma unroll
    for (int h = 1; h < 16; h <<= 1) {
        #pragma unroll
        for (int i = 0; i < 16; i += 2 * h) {
            #pragma unroll
            for (int k = 0; k < h; ++k) {
                float4 a = v[i + k], b = v[i + k + h];
                v[i + k] = add4(a, b);
                v[i + k + h] = sub4(a, b);
            }
        }
    }

    // Two halves (k[3] = quad bit 12), each through 64 KB LDS with 3 exchanges.
    // Within-half quad addr a = k[2:0]<<9 | t  (12 bits, 4096 quads).
    #pragma unroll
    for (int hf = 0; hf < 2; ++hf) {
        float4* u = v + hf * 8;
        if (hf) __syncthreads();                     // half-0 ExC reads done
        #pragma unroll
        for (int k2 = 0; k2 < 8; ++k2)
            lds4[SWZ((k2 << 9) | t)] = u[k2];
        __syncthreads();

        // Exchange A: vary a[2:0] (float bits 2..4)
        #pragma unroll
        for (int j = 0; j < 8; ++j) u[j] = lds4[SWZ((t << 3) | j)];
        lad3(u);
        #pragma unroll
        for (int j = 0; j < 8; ++j) lds4[SWZ((t << 3) | j)] = u[j];
        __syncthreads();

        // Exchange B: vary a[5:3] (float bits 5..7)
        const int bB = ((t >> 3) << 6) | (t & 7);
        #pragma unroll
        for (int j = 0; j < 8; ++j) u[j] = lds4[SWZ(bB | (j << 3))];
        lad3(u);
        #pragma unroll
        for (int j = 0; j < 8; ++j) lds4[SWZ(bB | (j << 3))] = u[j];
        __syncthreads();

        // Exchange C: vary a[8:6] (float bits 8..10), then store to global
        const int bC = ((t >> 6) << 9) | (t & 63);
        #pragma unroll
        for (int j = 0; j < 8; ++j) u[j] = lds4[SWZ(bC | (j << 6))];
        lad3(u);
        #pragma unroll
        for (int j = 0; j < 8; ++j)
            out4[(hf << 12) | bC | (j << 6)] = u[j];   // 64-quad contiguous/wave
    }
}

// ---------------- Pass 2: bits 15..25 ----------------
// Block: 32 columns x 2048 rows (row stride 2^15 floats). 1024 threads.
// Thread (c=t&31, g=t>>5) holds rows g+32j, j=0..63 in v[64].
// Phase A: 6-bit ladder over j (global bits 20..25).
// Two 128KB LDS chunks (32 j-values each); ALL threads read back one
// (j_local, c) column of 32 s-values, ladder bits 15..19, store full lines.
__global__ __launch_bounds__(1024) void fwht_high11(float* __restrict__ data) {
    __shared__ float lds[32768];                     // 128 KB
    const int t = threadIdx.x;
    const int c = t & 31;
    const int g = t >> 5;                            // 0..31 (reused as j_local)
    const size_t col = (size_t)blockIdx.x * 32 + c;

    float v[64];
    #pragma unroll
    for (int j = 0; j < 64; ++j)
        v[j] = data[((size_t)(g + 32 * j) << 15) + col];

    // Phase A: bits 20..25 over j
    #pragma unroll
    for (int h = 1; h < 64; h <<= 1) {
        #pragma unroll
        for (int i = 0; i < 64; i += 2 * h) {
            #pragma unroll
            for (int k = 0; k < h; ++k) {
                float a = v[i + k], b = v[i + k + h];
                v[i + k] = a + b;
                v[i + k + h] = a - b;
            }
        }
    }

    // Two chunks: transpose through LDS, ladder bits 15..19, store.
    #pragma unroll
    for (int m = 0; m < 2; ++m) {
        if (m) __syncthreads();                      // chunk-0 readers done
        #pragma unroll
        for (int jj = 0; jj < 32; ++jj)
            lds[jj * 1024 + g * 32 + c] = v[32 * m + jj];   // bank = c, free
        __syncthreads();

        float w[32];
        #pragma unroll
        for (int s = 0; s < 32; ++s)
            w[s] = lds[g * 1024 + s * 32 + c];       // j_local = g; bank = c, free
        // Phase B: bits 15..19 over s
        #pragma unroll
        for (int h = 1; h < 32; h <<= 1) {
            #pragma unroll
            for (int i = 0; i < 32; i += 2 * h) {
                #pragma unroll
                for (int k = 0; k < h; ++k) {
                    float a = w[i + k], b = w[i + k + h];
                    w[i + k] = a + b;
                    w[i + k + h] = a - b;
                }
            }
        }
        const int rowbase = 32 * (32 * m + g);
        #pragma unroll
        for (int s = 0; s < 32; ++s)
            __builtin_nontemporal_store(w[s], &data[((size_t)(rowbase + s) << 15) + col]);
    }
}

extern "C" void kernel_launch(void* const* d_in, const int* in_sizes, int n_in,
                              void* d_out, int out_size, void* d_ws, size_t ws_size,
                              hipStream_t stream) {
    const float* x = (const float*)d_in[0];
    float* out = (float*)d_out;
    fwht_low15<<<2048, 512, 0, stream>>>(x, out);    // bits 0..14, in -> out
    fwht_high11<<<1024, 1024, 0, stream>>>(out);     // bits 15..25, in place
}

// Round 7
// 189.438 us; speedup vs baseline: 2.2507x; 1.0027x over previous
//
#include <hip/hip_runtime.h>

// FWHT of 2^26 fp32 in TWO fully line-coalesced passes:
//   Pass 1 (fwht_low15): bits 0..14 — 512-thread blocks over 2^15 floats,
//       64 KB LDS (2 blocks/CU).
//       regs: bits 0,1 (intra-float4) + bits 11..14 (16-quad k-ladder)
//       LDS : 3 exchanges (A/B/C), each a b128 quad-transpose giving 3 bits
//             (float bits 2..4, 5..7, 8..10), XOR-swizzled conflict-free.
//   Pass 2 (fwht_high11): bits 15..25 — 32-col x 2048-row blocks (full 128B lines).
//       regs: bits 20..25 ; LDS: 2 x 128KB transpose chunks ; regs: bits 15..19.
// All butterfly stages commute; sum goes to the lower index (matches reference).
//
// Cache policy: the 256 MB data buffer == Infinity-Cache size. Input loads are
// nontemporal (read once, don't thrash L3); ALL stores and pass-2 loads are
// regular, so the intermediate (and across graph replays, the whole buffer)
// stays L3-resident and HBM traffic approaches input-read-only steady state.

typedef float nvf4 __attribute__((ext_vector_type(4)));

__device__ __forceinline__ float4 add4(float4 a, float4 b) {
    return make_float4(a.x + b.x, a.y + b.y, a.z + b.z, a.w + b.w);
}
__device__ __forceinline__ float4 sub4(float4 a, float4 b) {
    return make_float4(a.x - b.x, a.y - b.y, a.z - b.z, a.w - b.w);
}
// LDS float4-index swizzle: bank-group = a[2:0] ^ a[5:3]; conflict-free for all
// access patterns below (consecutive 8 lanes always hit 8 distinct groups).
__device__ __forceinline__ int SWZ(int q) { return q ^ ((q >> 3) & 7); }

// 3-stage FWHT ladder over u[0..7] (float4 SIMD)
__device__ __forceinline__ void lad3(float4* u) {
    #pragma unroll
    for (int h = 1; h < 8; h <<= 1) {
        #pragma unroll
        for (int i = 0; i < 8; i += 2 * h) {
            #pragma unroll
            for (int k = 0; k < h; ++k) {
                float4 a = u[i + k], b = u[i + k + h];
                u[i + k] = add4(a, b);
                u[i + k + h] = sub4(a, b);
            }
        }
    }
}

// ---------------- Pass 1: bits 0..14 ----------------
__global__ __launch_bounds__(512) void fwht_low15(const float* __restrict__ in,
                                                  float* __restrict__ out) {
    __shared__ float4 lds4[4096];                    // 64 KB (one half-block)
    const int t = threadIdx.x;                       // 0..511
    const size_t base4 = (size_t)blockIdx.x * 8192;  // float4 units
    const nvf4* in4 = reinterpret_cast<const nvf4*>(in) + base4;
    float4* out4 = reinterpret_cast<float4*>(out) + base4;

    float4 v[16];
    // Load 16 quads (nontemporal: read once) + intra-quad butterflies (bits 0,1)
    #pragma unroll
    for (int k = 0; k < 16; ++k) {
        nvf4 xv = __builtin_nontemporal_load(in4 + t + 512 * k);
        float a0 = xv[0] + xv[1], a1 = xv[0] - xv[1];
        float a2 = xv[2] + xv[3], a3 = xv[2] - xv[3];
        v[k] = make_float4(a0 + a2, a1 + a3, a0 - a2, a1 - a3);
    }
    // k-ladder: quad bits 9..12 = float bits 11..14
    #pragma unroll
    for (int h = 1; h < 16; h <<= 1) {
        #pragma unroll
        for (int i = 0; i < 16; i += 2 * h) {
            #pragma unroll
            for (int k = 0; k < h; ++k) {
                float4 a = v[i + k], b = v[i + k + h];
                v[i + k] = add4(a, b);
                v[i + k + h] = sub4(a, b);
            }
        }
    }

    // Two halves (k[3] = quad bit 12), each through 64 KB LDS with 3 exchanges.
    // Within-half quad addr a = k[2:0]<<9 | t  (12 bits, 4096 quads).
    #pragma unroll
    for (int hf = 0; hf < 2; ++hf) {
        float4* u = v + hf * 8;
        if (hf) __syncthreads();                     // half-0 ExC reads done
        #pragma unroll
        for (int k2 = 0; k2 < 8; ++k2)
            lds4[SWZ((k2 << 9) | t)] = u[k2];
        __syncthreads();

        // Exchange A: vary a[2:0] (float bits 2..4)
        #pragma unroll
        for (int j = 0; j < 8; ++j) u[j] = lds4[SWZ((t << 3) | j)];
        lad3(u);
        #pragma unroll
        for (int j = 0; j < 8; ++j) lds4[SWZ((t << 3) | j)] = u[j];
        __syncthreads();

        // Exchange B: vary a[5:3] (float bits 5..7)
        const int bB = ((t >> 3) << 6) | (t & 7);
        #pragma unroll
        for (int j = 0; j < 8; ++j) u[j] = lds4[SWZ(bB | (j << 3))];
        lad3(u);
        #pragma unroll
        for (int j = 0; j < 8; ++j) lds4[SWZ(bB | (j << 3))] = u[j];
        __syncthreads();

        // Exchange C: vary a[8:6] (float bits 8..10), then store to global
        const int bC = ((t >> 6) << 9) | (t & 63);
        #pragma unroll
        for (int j = 0; j < 8; ++j) u[j] = lds4[SWZ(bC | (j << 6))];
        lad3(u);
        #pragma unroll
        for (int j = 0; j < 8; ++j)
            out4[(hf << 12) | bC | (j << 6)] = u[j];   // regular: keep in L3
    }
}

// ---------------- Pass 2: bits 15..25 ----------------
// Block: 32 columns x 2048 rows (row stride 2^15 floats). 1024 threads.
// Thread (c=t&31, g=t>>5) holds rows g+32j, j=0..63 in v[64].
// Phase A: 6-bit ladder over j (global bits 20..25).
// Two 128KB LDS chunks (32 j-values each); ALL threads read back one
// (j_local, c) column of 32 s-values, ladder bits 15..19, store full lines.
__global__ __launch_bounds__(1024) void fwht_high11(float* __restrict__ data) {
    __shared__ float lds[32768];                     // 128 KB
    const int t = threadIdx.x;
    const int c = t & 31;
    const int g = t >> 5;                            // 0..31 (reused as j_local)
    const size_t col = (size_t)blockIdx.x * 32 + c;

    float v[64];
    #pragma unroll
    for (int j = 0; j < 64; ++j)
        v[j] = data[((size_t)(g + 32 * j) << 15) + col];   // regular: L3 hits

    // Phase A: bits 20..25 over j
    #pragma unroll
    for (int h = 1; h < 64; h <<= 1) {
        #pragma unroll
        for (int i = 0; i < 64; i += 2 * h) {
            #pragma unroll
            for (int k = 0; k < h; ++k) {
                float a = v[i + k], b = v[i + k + h];
                v[i + k] = a + b;
                v[i + k + h] = a - b;
            }
        }
    }

    // Two chunks: transpose through LDS, ladder bits 15..19, store.
    #pragma unroll
    for (int m = 0; m < 2; ++m) {
        if (m) __syncthreads();                      // chunk-0 readers done
        #pragma unroll
        for (int jj = 0; jj < 32; ++jj)
            lds[jj * 1024 + g * 32 + c] = v[32 * m + jj];   // bank = c, free
        __syncthreads();

        float w[32];
        #pragma unroll
        for (int s = 0; s < 32; ++s)
            w[s] = lds[g * 1024 + s * 32 + c];       // j_local = g; bank = c, free
        // Phase B: bits 15..19 over s
        #pragma unroll
        for (int h = 1; h < 32; h <<= 1) {
            #pragma unroll
            for (int i = 0; i < 32; i += 2 * h) {
                #pragma unroll
                for (int k = 0; k < h; ++k) {
                    float a = w[i + k], b = w[i + k + h];
                    w[i + k] = a + b;
                    w[i + k + h] = a - b;
                }
            }
        }
        const int rowbase = 32 * (32 * m + g);
        #pragma unroll
        for (int s = 0; s < 32; ++s)
            data[((size_t)(rowbase + s) << 15) + col] = w[s];   // regular: stay in L3
    }
}

extern "C" void kernel_launch(void* const* d_in, const int* in_sizes, int n_in,
                              void* d_out, int out_size, void* d_ws, size_t ws_size,
                              hipStream_t stream) {
    const float* x = (const float*)d_in[0];
    float* out = (float*)d_out;
    fwht_low15<<<2048, 512, 0, stream>>>(x, out);    // bits 0..14, in -> out
    fwht_high11<<<1024, 1024, 0, stream>>>(out);     // bits 15..25, in place
}